// Round 7
// baseline (407.256 us; speedup 1.0000x reference)
//
#include <hip/hip_runtime.h>

// CausalSelfAttention: B=2, S=2048, H=2048, NH=16, HD=128. f32 in/out, bf16 MFMA inside.
// R15 = R14 geometry (256x192 QKV = 512 blk 2 exact rounds; 256x128 outproj = 256 blk)
// with the K-loop replaced by a faithful port of the m201 8-phase lockstep:
//   per K-tile 4 phases, each {ds_reads for THIS phase (+stage burst at ph0) ->
//   barrier -> lgkmcnt(0) -> setprio(1) + MFMA cluster + setprio(0) -> barrier}.
//   Stage(t+1) bursts at ph0 into the buffer freed by t-1's final barrier; the
//   vmcnt(0) certification sits at ph3, 3 phases (~2400cy) after issue (>> 900cy
//   HBM latency) -> drain is certification, not stall. 8 barriers/tile (m201's
//   density). R14's counted-lgkm read-ahead removed (measured neutral vs R10;
//   m196 says the per-phase lockstep interleave is the lever, +7-27%).
// T2 swizzle (conflicts=0 measured), epilogue pack formulas, XCD clustering,
// fused [6144][2048] B with per-column z-select: verbatim from R14 (verified).
// attn_kernel / convert_x / convert_wt unchanged from R9/R11 (verified).

using bf16x8 = __attribute__((ext_vector_type(8))) short;
using bf16x4 = __attribute__((ext_vector_type(4))) short;
using f32x4  = __attribute__((ext_vector_type(4))) float;

#define S_LEN 2048
#define NHEAD 16
#define HDIM  128
#define HID   2048

__device__ __forceinline__ unsigned short f2bf(float f) {
    unsigned int u = __float_as_uint(f);
    u += 0x7fffu + ((u >> 16) & 1u);   // round-to-nearest-even
    return (unsigned short)(u >> 16);
}
__device__ __forceinline__ void gl2lds16(const void* g, void* l) {
    __builtin_amdgcn_global_load_lds(
        (const __attribute__((address_space(1))) void*)g,
        (__attribute__((address_space(3))) void*)l, 16, 0, 0);
}

// 16x16x16 bf16 MFMA, device-guarded (host pass must not reference the builtin).
__device__ __forceinline__ f32x4 pv_mfma(bf16x4 a, bf16x4 b, f32x4 c) {
#if defined(__HIP_DEVICE_COMPILE__)
#if __has_builtin(__builtin_amdgcn_mfma_f32_16x16x16bf16_1k)
    return __builtin_amdgcn_mfma_f32_16x16x16bf16_1k(a, b, c, 0, 0, 0);
#else
    asm("v_mfma_f32_16x16x16_bf16 %0, %1, %2, %0" : "+v"(c) : "v"(a), "v"(b));
    return c;
#endif
#else
    (void)a; (void)b;
    return c;
#endif
}

// ---------------------------------------------------------------- convert x: f32 -> bf16
__global__ void convert_x(const float* __restrict__ x, unsigned short* __restrict__ xb) {
    int i = (blockIdx.x * 256 + threadIdx.x) * 4;
    float4 v = *(const float4*)(x + i);
    ushort4 o;
    o.x = f2bf(v.x); o.y = f2bf(v.y); o.z = f2bf(v.z); o.w = f2bf(v.w);
    *(ushort4*)(xb + i) = o;
}

// ------------------------------------------------- convert+transpose weights: f32 -> bf16^T
__global__ void convert_wt(const float* __restrict__ w0, const float* __restrict__ w1,
                           const float* __restrict__ w2, const float* __restrict__ w3,
                           unsigned short* __restrict__ t0, unsigned short* __restrict__ t1,
                           unsigned short* __restrict__ t2, unsigned short* __restrict__ t3) {
    __shared__ float tile[64][65];
    int z = blockIdx.z;
    const float* src = (z == 0) ? w0 : (z == 1) ? w1 : (z == 2) ? w2 : w3;
    unsigned short* dst = (z == 0) ? t0 : (z == 1) ? t1 : (z == 2) ? t2 : t3;
    int r0 = blockIdx.y * 64, c0 = blockIdx.x * 64;
    int t = threadIdx.x;
    for (int i = t; i < 64 * 64; i += 256) {
        int r = i >> 6, c = i & 63;
        tile[r][c] = src[(size_t)(r0 + r) * HID + c0 + c];
    }
    __syncthreads();
    for (int i = t; i < 64 * 64; i += 256) {
        int r = i & 63, c = i >> 6;
        dst[(size_t)(c0 + c) * HID + r0 + r] = f2bf(tile[r][c]);
    }
}

// ---- sync helpers -----------------------------------------------------------
__device__ __forceinline__ void sched0() { __builtin_amdgcn_sched_barrier(0); }
__device__ __forceinline__ void w_lgkm0() { asm volatile("s_waitcnt lgkmcnt(0)" ::: "memory"); sched0(); }
__device__ __forceinline__ void w_vm0()   { asm volatile("s_waitcnt vmcnt(0)" ::: "memory");   sched0(); }
__device__ __forceinline__ void barx() {
    asm volatile("" ::: "memory");
    __builtin_amdgcn_s_barrier();
    asm volatile("" ::: "memory");
}

// ---------------------------------------------------------------- GEMM 256xBN (R15)
// C[4096][N] = A @ Bt^T + bias; A,Bt bf16, fp32 acc. BN = NJ*64.
// MODE 1: fused QKV, N=6144, Bt0 = contiguous [6144][2048]. NJ=3 -> grid 512 (2 rounds).
// MODE 0: out-proj, N=2048, f32 out. NJ=2 -> grid 256 (1 round).
template <int MODE, int NJ>
__launch_bounds__(512, 2)
__global__ void gemmT(const unsigned short* __restrict__ A,
                      const unsigned short* __restrict__ Bt0,
                      const float* __restrict__ bias0,
                      const float* __restrict__ bias1,
                      const float* __restrict__ bias2,
                      unsigned short* __restrict__ C0,
                      unsigned short* __restrict__ C1,
                      unsigned short* __restrict__ C2,
                      float* __restrict__ Cf) {
    constexpr int BN = NJ * 64;
    // LDS: A 256x64 (32KB) x2 + B BNx64 x2.  NJ=3: 112KB, NJ=2: 96KB -> 1 blk/CU.
    __shared__ __align__(16) unsigned short lds[2 * 16384 + 2 * NJ * 4096];
    unsigned short* const A0 = lds;
    unsigned short* const A1 = lds + 16384;
    unsigned short* const B0 = lds + 32768;
    unsigned short* const B1 = lds + 32768 + NJ * 4096;

    const int CPX = (MODE == 1) ? 64 : 32;      // blocks per XCD (bijective: nwg%8==0)
    int vb = (blockIdx.x & 7) * CPX + (blockIdx.x >> 3);
    int m0  = (vb & 15) * 256;
    int n0g = (vb >> 4) * BN;                   // fused col (0..6143 / 0..2047)

    int tid = threadIdx.x;
    int lane = tid & 63;
    int wv_ = tid >> 6;
    int wr = wv_ >> 2, wc = wv_ & 3;            // 2x4 wave grid; wave tile 128 x (NJ*16)
    int l15 = lane & 15, quad = lane >> 4;

    // ---- staging: 512 thr x 16B = 64 rows/issue. A: 4 issues, B: NJ issues.
    // T2 pre-swizzled source (verified, conflicts=0): LDS slot s gets col (s^row&7).
    int tr = tid >> 3;
    int tc = ((tid & 7) ^ (tr & 7)) << 3;
    const unsigned short* gA = A   + (size_t)(m0  + tr) * HID + tc;
    const unsigned short* gB = Bt0 + (size_t)(n0g + tr) * HID + tc;
    const int td8 = tid * 8;

    // ---- fragment ds_read offsets (read swizzle = store swizzle).
    int arow0 = (wr * 128 + l15) * 64;          // + mi*1024
    int brow0 = (wc * (16 * NJ) + l15) * 64;    // + nj*1024
    int sw0 = ((quad ^ (l15 & 7)) << 3);        // kk=0
    int sw1 = (((4 + quad) ^ (l15 & 7)) << 3);  // kk=1

    f32x4 acc[8][NJ];
#pragma unroll
    for (int i = 0; i < 8; ++i)
#pragma unroll
        for (int j = 0; j < NJ; ++j) acc[i][j] = (f32x4){0.f, 0.f, 0.f, 0.f};

    bf16x8 aV[4], bv0[NJ], bv1[NJ];

#define STAGE(kt, AD, BD) do { int _kc = (kt) * 64;                          \
    gl2lds16(gA + _kc,             (AD) + td8);                              \
    gl2lds16(gA + 64 * HID + _kc,  (AD) + 4096 + td8);                       \
    gl2lds16(gA + 128 * HID + _kc, (AD) + 8192 + td8);                       \
    gl2lds16(gA + 192 * HID + _kc, (AD) + 12288 + td8);                      \
    _Pragma("unroll")                                                        \
    for (int _r = 0; _r < NJ; ++_r)                                          \
        gl2lds16(gB + (size_t)(_r * 64) * HID + _kc, (BD) + _r * 4096 + td8); } while (0)

#define LDA4(AD, QB, SW) do {                                                \
    aV[0] = *(const bf16x8*)((AD) + arow0 + ((QB) + 0) * 1024 + (SW));       \
    aV[1] = *(const bf16x8*)((AD) + arow0 + ((QB) + 1) * 1024 + (SW));       \
    aV[2] = *(const bf16x8*)((AD) + arow0 + ((QB) + 2) * 1024 + (SW));       \
    aV[3] = *(const bf16x8*)((AD) + arow0 + ((QB) + 3) * 1024 + (SW)); } while (0)

#define LDB(dst, BD, SW) do {                                                \
    _Pragma("unroll")                                                        \
    for (int _n = 0; _n < NJ; ++_n)                                          \
        dst[_n] = *(const bf16x8*)((BD) + brow0 + _n * 1024 + (SW)); } while (0)

#define MF(Q, b) do {                                                        \
    __builtin_amdgcn_s_setprio(1);                                           \
    _Pragma("unroll")                                                        \
    for (int mi = 0; mi < 4; ++mi)                                           \
        _Pragma("unroll")                                                    \
        for (int nj = 0; nj < NJ; ++nj)                                      \
            acc[(Q) * 4 + mi][nj] =                                          \
                __builtin_amdgcn_mfma_f32_16x16x32_bf16(aV[mi], b[nj],       \
                                                        acc[(Q) * 4 + mi][nj], 0, 0, 0); \
    __builtin_amdgcn_s_setprio(0); sched0(); } while (0)

    // One K-tile in (AD,BD); stage ks=t+1 into (AN,BN_) at ph0 (freed by the
    // final barrier of tile t-1); certify via vmcnt(0) at ph3 (3 phases after
    // issue, >> HBM latency). 4 phases, 8 barriers, m201 lockstep.
#define KTILE(AD, BD, AN, BN_, ks) do {                                      \
    /* ph0 */                                                                \
    LDA4(AD, 0, sw0); LDB(bv0, BD, sw0);                                     \
    STAGE(ks, AN, BN_);                                                      \
    barx(); w_lgkm0();                                                       \
    MF(0, bv0);                                                              \
    barx();                                                                  \
    /* ph1 */                                                                \
    LDA4(AD, 4, sw0);                                                        \
    barx(); w_lgkm0();                                                       \
    MF(1, bv0);                                                              \
    barx();                                                                  \
    /* ph2 */                                                                \
    LDA4(AD, 0, sw1); LDB(bv1, BD, sw1);                                     \
    barx(); w_lgkm0();                                                       \
    MF(0, bv1);                                                              \
    barx();                                                                  \
    /* ph3 */                                                                \
    LDA4(AD, 4, sw1);                                                        \
    barx(); w_lgkm0();                                                       \
    MF(1, bv1);                                                              \
    w_vm0();                         /* stage(ks) certified for all waves */ \
    barx();                                                                  \
} while (0)

    // prologue: stage tile0, certify.
    STAGE(0, A0, B0);
    w_vm0();
    barx();

    for (int t = 0; t < 32; t += 2) {
        KTILE(A0, B0, A1, B1, t + 1);
        KTILE(A1, B1, A0, B0, (t + 2 < 32) ? t + 2 : 31);   // last: dummy restage
    }
    asm volatile("s_waitcnt vmcnt(0) lgkmcnt(0)" ::: "memory");

#undef KTILE
#undef STAGE
#undef LDA4
#undef LDB
#undef MF

    // ---- epilogue (pack formulas verbatim; z selected per column for fused tiles)
#pragma unroll
    for (int j = 0; j < NJ; ++j) {
        int n = n0g + wc * (16 * NJ) + j * 16 + l15;    // fused col
        int zj = (MODE == 1) ? (n >> 11) : 0;
        int nn = (MODE == 1) ? (n & 2047) : n;
        float bn = (MODE == 1)
                     ? ((zj == 0) ? bias0[nn] : (zj == 1) ? bias1[nn] : bias2[nn])
                     : bias0[nn];
        unsigned short* Cz = (zj == 0) ? C0 : (zj == 1) ? C1 : C2;
#pragma unroll
        for (int i = 0; i < 8; ++i) {
            int mb = m0 + wr * 128 + i * 16 + quad * 4;   // base row, regs = mb..mb+3
            if (MODE == 1 && zj == 2) {
                // V-pack: 4 regs = 4 consecutive keys (e=0..3) -> one ushort4.
                int b = mb >> 11, s = mb & 2047, h = nn >> 7, d = nn & 127;
                int kt = s >> 4, qv = (s >> 2) & 3, ct = d >> 4, lv = d & 15;
                size_t addr = ((((size_t)((b << 4) + h) * 128 + kt) * 4 + (ct >> 1)) * 4 + qv) * 128
                              + lv * 8 + (ct & 1) * 4;
                ushort4 o;
                o.x = f2bf(acc[i][j][0] + bn);
                o.y = f2bf(acc[i][j][1] + bn);
                o.z = f2bf(acc[i][j][2] + bn);
                o.w = f2bf(acc[i][j][3] + bn);
                *(ushort4*)&Cz[addr] = o;
            } else {
#pragma unroll
                for (int reg = 0; reg < 4; ++reg) {
                    int m = mb + reg;
                    float v = acc[i][j][reg] + bn;
                    if (MODE == 0) {
                        Cf[(size_t)m * HID + nn] = v;
                    } else {
                        int b = m >> 11, s = m & 2047, h = nn >> 7, d = nn & 127;
                        if (zj == 1) {
                            // K-pack: key=s -> (kt, lk); d -> (kk, qk, e)
                            int kt = s >> 4, lk = s & 15, kk = d >> 5, qk = (d >> 3) & 3, e = d & 7;
                            size_t addr = ((((size_t)((b << 4) + h) * 128 + kt) * 4 + kk) * 4 + qk) * 128
                                          + lk * 8 + e;
                            Cz[addr] = f2bf(v);
                        } else {
                            Cz[(size_t)(((b << 4) + h) * S_LEN + s) * HDIM + d] = f2bf(v);
                        }
                    }
                }
            }
        }
    }
}

// ---------------------------------------------------------------- flash attention (R9, unchanged)
__launch_bounds__(256, 4)
__global__ void attn_kernel(const unsigned short* __restrict__ Qg,
                            const unsigned short* __restrict__ Kp,
                            const unsigned short* __restrict__ Vp,
                            unsigned short* __restrict__ O) {
    int linear = blockIdx.y * 32 + blockIdx.x;   // 0..1023
    int xcd = linear & 7;
    int u = linear >> 3;                          // 0..127
    int bh = xcd * 4 + (u & 3);                   // 4 bh per XCD
    int j = u >> 2;                               // 0..31
    int b = bh >> 4, h = bh & 15;

    int tid = threadIdx.x, lane = tid & 63, w = tid >> 6;
    int l15 = lane & 15, quad = lane >> 4;

    int role = (w + (u >> 5)) & 3;                // per-CU-varying rotation
    int strip = (role < 2) ? (2 * j + role) : (126 - 2 * j + (role - 2));
    int r0 = strip * 16;

    const unsigned short* Qb = Qg + (size_t)bh * (S_LEN * HDIM);
    const unsigned short* Kb = Kp + (size_t)bh * 262144 + quad * 128 + l15 * 8;
    const unsigned short* Vb = Vp + (size_t)bh * 262144 + quad * 128 + l15 * 8;

    bf16x8 qf[4];
#pragma unroll
    for (int kk = 0; kk < 4; ++kk)
        qf[kk] = *(const bf16x8*)&Qb[(size_t)(r0 + l15) * HDIM + kk * 32 + quad * 8];

    f32x4 o_acc[8];
#pragma unroll
    for (int c = 0; c < 8; ++c) o_acc[c] = (f32x4){0.f, 0.f, 0.f, 0.f};
    float l_part = 0.f;

    const float k2 = 0.08838834764831845f * 1.4426950408889634f;  // scale*log2(e)

    int nkt = strip + 1;

    bf16x8 kA[4], kB[4], v[4];

#define LOADK(dst, t) do { size_t _o = (size_t)(t) * 2048;                         \
    dst[0] = *(const bf16x8*)&Kb[_o];                                              \
    dst[1] = *(const bf16x8*)&Kb[_o + 512];                                        \
    dst[2] = *(const bf16x8*)&Kb[_o + 1024];                                       \
    dst[3] = *(const bf16x8*)&Kb[_o + 1536]; } while (0)

#define LOADV(dst, t) do { size_t _o = (size_t)(t) * 2048;                         \
    dst[0] = *(const bf16x8*)&Vb[_o];                                              \
    dst[1] = *(const bf16x8*)&Vb[_o + 512];                                        \
    dst[2] = *(const bf16x8*)&Vb[_o + 1024];                                       \
    dst[3] = *(const bf16x8*)&Vb[_o + 1536]; } while (0)

#define VLO(x) __builtin_shufflevector(x, x, 0, 1, 2, 3)
#define VHI(x) __builtin_shufflevector(x, x, 4, 5, 6, 7)

#define TILE(kreg, t) do {                                                         \
    f32x4 st0 = (f32x4){0.f, 0.f, 0.f, 0.f};                                       \
    f32x4 st1 = (f32x4){0.f, 0.f, 0.f, 0.f};                                       \
    st0 = __builtin_amdgcn_mfma_f32_16x16x32_bf16(kreg[0], qf[0], st0, 0, 0, 0);   \
    st1 = __builtin_amdgcn_mfma_f32_16x16x32_bf16(kreg[1], qf[1], st1, 0, 0, 0);   \
    st0 = __builtin_amdgcn_mfma_f32_16x16x32_bf16(kreg[2], qf[2], st0, 0, 0, 0);   \
    st1 = __builtin_amdgcn_mfma_f32_16x16x32_bf16(kreg[3], qf[3], st1, 0, 0, 0);   \
    f32x4 stv = st0 + st1;                                                         \
    float p0, p1, p2, p3;                                                          \
    if ((t) == nkt - 1) {                                                          \
        p0 = (quad * 4 + 0 <= l15) ? exp2f(stv[0] * k2) : 0.f;                     \
        p1 = (quad * 4 + 1 <= l15) ? exp2f(stv[1] * k2) : 0.f;                     \
        p2 = (quad * 4 + 2 <= l15) ? exp2f(stv[2] * k2) : 0.f;                     \
        p3 = (quad * 4 + 3 <= l15) ? exp2f(stv[3] * k2) : 0.f;                     \
    } else {                                                                       \
        p0 = exp2f(stv[0] * k2); p1 = exp2f(stv[1] * k2);                          \
        p2 = exp2f(stv[2] * k2); p3 = exp2f(stv[3] * k2);                          \
    }                                                                              \
    l_part += (p0 + p1) + (p2 + p3);                                               \
    bf16x4 pf;                                                                     \
    pf[0] = (short)f2bf(p0); pf[1] = (short)f2bf(p1);                              \
    pf[2] = (short)f2bf(p2); pf[3] = (short)f2bf(p3);                              \
    o_acc[0] = pv_mfma(pf, VLO(v[0]), o_acc[0]);                                   \
    o_acc[1] = pv_mfma(pf, VHI(v[0]), o_acc[1]);                                   \
    o_acc[2] = pv_mfma(pf, VLO(v[1]), o_acc[2]);                                   \
    o_acc[3] = pv_mfma(pf, VHI(v[1]), o_acc[3]);                                   \
    o_acc[4] = pv_mfma(pf, VLO(v[2]), o_acc[4]);                                   \
    o_acc[5] = pv_mfma(pf, VHI(v[2]), o_acc[5]);                                   \
    o_acc[6] = pv_mfma(pf, VLO(v[3]), o_acc[6]);                                   \
    o_acc[7] = pv_mfma(pf, VHI(v[3]), o_acc[7]);                                   \
} while (0)

    LOADK(kA, 0);
    int kt = 0;
    while (true) {
        int ktn = (kt + 1 < nkt) ? kt + 1 : kt;
        LOADV(v, kt);
        LOADK(kB, ktn);
        TILE(kA, kt);
        if (++kt >= nkt) break;

        ktn = (kt + 1 < nkt) ? kt + 1 : kt;
        LOADV(v, kt);
        LOADK(kA, ktn);
        TILE(kB, kt);
        if (++kt >= nkt) break;
    }

#undef TILE
#undef LOADK
#undef LOADV
#undef VLO
#undef VHI

    l_part += __shfl_xor(l_part, 16, 64);
    l_part += __shfl_xor(l_part, 32, 64);

#pragma unroll
    for (int reg = 0; reg < 4; ++reg) {
        float l = __shfl(l_part, quad * 4 + reg, 64);
        float inv = 1.f / l;
        int srow = r0 + quad * 4 + reg;
        unsigned short* op = O + (size_t)(b * S_LEN + srow) * HID + h * HDIM;
#pragma unroll
        for (int ct = 0; ct < 8; ++ct)
            op[ct * 16 + l15] = f2bf(o_acc[ct][reg] * inv);
    }
}

// ---------------------------------------------------------------- launch
extern "C" void kernel_launch(void* const* d_in, const int* in_sizes, int n_in,
                              void* d_out, int out_size, void* d_ws, size_t ws_size,
                              hipStream_t stream) {
    (void)in_sizes; (void)n_in; (void)out_size; (void)ws_size;
    const float* x  = (const float*)d_in[0];
    const float* wq = (const float*)d_in[2];
    const float* bq = (const float*)d_in[3];
    const float* wk = (const float*)d_in[4];
    const float* bk = (const float*)d_in[5];
    const float* wv = (const float*)d_in[6];
    const float* bv = (const float*)d_in[7];
    const float* wo = (const float*)d_in[8];
    const float* bo = (const float*)d_in[9];
    float* out = (float*)d_out;

    unsigned short* ws = (unsigned short*)d_ws;
    const size_t WSZ = 4194304;
    unsigned short* wqT = ws;                // [0, 4M)   wqT/wkT/wvT contiguous =
    unsigned short* wkT = ws + WSZ;          // [4M, 8M)  fused [6144][2048] B for QKV
    unsigned short* wvT = ws + 2 * WSZ;      // [8M, 12M)
    unsigned short* woT = ws + 3 * WSZ;      // [12M, 16M)
    unsigned short* xb  = ws + 4 * WSZ;      // [16M, 24M)
    unsigned short* Ab  = ws + 4 * WSZ;      // aliases xb (dead after QKV gemm)
    unsigned short* Qb  = ws + 6 * WSZ;      // [24M, 32M)
    unsigned short* Kb  = ws + 8 * WSZ;      // [32M, 40M)  fragment-packed
    unsigned short* Vb  = ws + 10 * WSZ;     // [40M, 48M)  fragment-packed

    convert_x<<<dim3(8192), 256, 0, stream>>>(x, xb);
    convert_wt<<<dim3(32, 32, 4), 256, 0, stream>>>(wq, wk, wv, wo, wqT, wkT, wvT, woT);
    gemmT<1, 3><<<dim3(512), 512, 0, stream>>>(xb, wqT, bq, bk, bv,
                                               Qb, Kb, Vb, nullptr);
    attn_kernel<<<dim3(32, 32), 256, 0, stream>>>(Qb, Kb, Vb, Ab);
    gemmT<0, 2><<<dim3(256), 512, 0, stream>>>(Ab, woT, bo, nullptr, nullptr,
                                               nullptr, nullptr, nullptr, out);
}

// Round 8
// 402.547 us; speedup vs baseline: 1.0117x; 1.0117x over previous
//
#include <hip/hip_runtime.h>

// CausalSelfAttention: B=2, S=2048, H=2048, NH=16, HD=128. f32 in/out, bf16 MFMA inside.
// R16 = R14 GEMM (best measured: counted-lgkm 256x192/256x128, exact rounds) +
// attn wave-balance rewrite. R15's lockstep regressed (serialization proven by
// cycle accounting) -> GEMM reverted to R14 verbatim and frozen.
// attn (R0 counters): occupancy 23% because per-block waves had trip counts
// {2j+1,2j+2,127-2j,128-2j} -> two waves exit immediately, block pinned by the
// longest. R16: strip pairs (p,127-p) per 2-wave team; wave0 = full strip p
// (p+1 tiles) + prefix of strip 127-p; wave1 = 64-tile suffix. EVERY wave
// 64-65 tiles. 4 blocks/CU x 4 waves = 16 equal waves/CU steady. Strip-B
// partials merged via conflict-free [64][33] LDS (raw o_acc+l_part add; no
// max-tracking -> exact reorder). One __syncthreads. Inner tile math/loads
// verbatim R9 (verified) + setprio around MFMA clusters (m191 attn +4-7%).
// convert_x / convert_wt unchanged.

using bf16x8 = __attribute__((ext_vector_type(8))) short;
using bf16x4 = __attribute__((ext_vector_type(4))) short;
using f32x4  = __attribute__((ext_vector_type(4))) float;

#define S_LEN 2048
#define NHEAD 16
#define HDIM  128
#define HID   2048

__device__ __forceinline__ unsigned short f2bf(float f) {
    unsigned int u = __float_as_uint(f);
    u += 0x7fffu + ((u >> 16) & 1u);   // round-to-nearest-even
    return (unsigned short)(u >> 16);
}
__device__ __forceinline__ void gl2lds16(const void* g, void* l) {
    __builtin_amdgcn_global_load_lds(
        (const __attribute__((address_space(1))) void*)g,
        (__attribute__((address_space(3))) void*)l, 16, 0, 0);
}

// 16x16x16 bf16 MFMA, device-guarded (host pass must not reference the builtin).
__device__ __forceinline__ f32x4 pv_mfma(bf16x4 a, bf16x4 b, f32x4 c) {
#if defined(__HIP_DEVICE_COMPILE__)
#if __has_builtin(__builtin_amdgcn_mfma_f32_16x16x16bf16_1k)
    return __builtin_amdgcn_mfma_f32_16x16x16bf16_1k(a, b, c, 0, 0, 0);
#else
    asm("v_mfma_f32_16x16x16_bf16 %0, %1, %2, %0" : "+v"(c) : "v"(a), "v"(b));
    return c;
#endif
#else
    (void)a; (void)b;
    return c;
#endif
}

// ---------------------------------------------------------------- convert x: f32 -> bf16
__global__ void convert_x(const float* __restrict__ x, unsigned short* __restrict__ xb) {
    int i = (blockIdx.x * 256 + threadIdx.x) * 4;
    float4 v = *(const float4*)(x + i);
    ushort4 o;
    o.x = f2bf(v.x); o.y = f2bf(v.y); o.z = f2bf(v.z); o.w = f2bf(v.w);
    *(ushort4*)(xb + i) = o;
}

// ------------------------------------------------- convert+transpose weights: f32 -> bf16^T
__global__ void convert_wt(const float* __restrict__ w0, const float* __restrict__ w1,
                           const float* __restrict__ w2, const float* __restrict__ w3,
                           unsigned short* __restrict__ t0, unsigned short* __restrict__ t1,
                           unsigned short* __restrict__ t2, unsigned short* __restrict__ t3) {
    __shared__ float tile[64][65];
    int z = blockIdx.z;
    const float* src = (z == 0) ? w0 : (z == 1) ? w1 : (z == 2) ? w2 : w3;
    unsigned short* dst = (z == 0) ? t0 : (z == 1) ? t1 : (z == 2) ? t2 : t3;
    int r0 = blockIdx.y * 64, c0 = blockIdx.x * 64;
    int t = threadIdx.x;
    for (int i = t; i < 64 * 64; i += 256) {
        int r = i >> 6, c = i & 63;
        tile[r][c] = src[(size_t)(r0 + r) * HID + c0 + c];
    }
    __syncthreads();
    for (int i = t; i < 64 * 64; i += 256) {
        int r = i & 63, c = i >> 6;
        dst[(size_t)(c0 + c) * HID + r0 + r] = f2bf(tile[r][c]);
    }
}

// ---- counted waits (asm literals need compile-time dispatch) -----------------
__device__ __forceinline__ void sched0() { __builtin_amdgcn_sched_barrier(0); }
__device__ __forceinline__ void w_lgkm4() { asm volatile("s_waitcnt lgkmcnt(4)" ::: "memory"); sched0(); }
__device__ __forceinline__ void w_lgkm0() { asm volatile("s_waitcnt lgkmcnt(0)" ::: "memory"); sched0(); }
template <int NJ> __device__ __forceinline__ void w_lgkm_4nj() {
    if constexpr (NJ == 3) { asm volatile("s_waitcnt lgkmcnt(7)" ::: "memory"); }
    else                   { asm volatile("s_waitcnt lgkmcnt(6)" ::: "memory"); }
    sched0();
}
template <int NJ> __device__ __forceinline__ void w_vm_ns() {
    if constexpr (NJ == 3) { asm volatile("s_waitcnt vmcnt(7)" ::: "memory"); }
    else                   { asm volatile("s_waitcnt vmcnt(6)" ::: "memory"); }
    sched0();
}
__device__ __forceinline__ void barx() {
    asm volatile("" ::: "memory");
    __builtin_amdgcn_s_barrier();
    asm volatile("" ::: "memory");
}

// ---------------------------------------------------------------- GEMM 256xBN (R14, frozen)
// C[4096][N] = A @ Bt^T + bias; A,Bt bf16, fp32 acc. BN = NJ*64.
// MODE 1: fused QKV, N=6144, Bt0 = contiguous [6144][2048]. NJ=3 -> grid 512 (2 rounds).
// MODE 0: out-proj, N=2048, f32 out. NJ=2 -> grid 256 (1 round).
template <int MODE, int NJ>
__launch_bounds__(512, 2)
__global__ void gemmT(const unsigned short* __restrict__ A,
                      const unsigned short* __restrict__ Bt0,
                      const float* __restrict__ bias0,
                      const float* __restrict__ bias1,
                      const float* __restrict__ bias2,
                      unsigned short* __restrict__ C0,
                      unsigned short* __restrict__ C1,
                      unsigned short* __restrict__ C2,
                      float* __restrict__ Cf) {
    constexpr int BN = NJ * 64;
    __shared__ __align__(16) unsigned short lds[2 * 16384 + 2 * NJ * 4096];
    unsigned short* const A0 = lds;
    unsigned short* const A1 = lds + 16384;
    unsigned short* const B0 = lds + 32768;
    unsigned short* const B1 = lds + 32768 + NJ * 4096;

    const int CPX = (MODE == 1) ? 64 : 32;      // blocks per XCD (bijective: nwg%8==0)
    int vb = (blockIdx.x & 7) * CPX + (blockIdx.x >> 3);
    int m0  = (vb & 15) * 256;
    int n0g = (vb >> 4) * BN;                   // fused col (0..6143 / 0..2047)

    int tid = threadIdx.x;
    int lane = tid & 63;
    int wv_ = tid >> 6;
    int wr = wv_ >> 2, wc = wv_ & 3;            // 2x4 wave grid; wave tile 128 x (NJ*16)
    int l15 = lane & 15, quad = lane >> 4;

    int tr = tid >> 3;
    int tc = ((tid & 7) ^ (tr & 7)) << 3;
    const unsigned short* gA = A   + (size_t)(m0  + tr) * HID + tc;
    const unsigned short* gB = Bt0 + (size_t)(n0g + tr) * HID + tc;
    const int td8 = tid * 8;

    int arow0 = (wr * 128 + l15) * 64;          // + mi*1024
    int brow0 = (wc * (16 * NJ) + l15) * 64;    // + nj*1024
    int sw0 = ((quad ^ (l15 & 7)) << 3);        // kk=0
    int sw1 = (((4 + quad) ^ (l15 & 7)) << 3);  // kk=1

    f32x4 acc[8][NJ];
#pragma unroll
    for (int i = 0; i < 8; ++i)
#pragma unroll
        for (int j = 0; j < NJ; ++j) acc[i][j] = (f32x4){0.f, 0.f, 0.f, 0.f};

    bf16x8 aX[4], aY[4], b0v[NJ], b1v[NJ];

#define STAGE(kt, AD, BD) do { int _kc = (kt) * 64;                          \
    gl2lds16(gA + _kc,             (AD) + td8);                              \
    gl2lds16(gA + 64 * HID + _kc,  (AD) + 4096 + td8);                       \
    gl2lds16(gA + 128 * HID + _kc, (AD) + 8192 + td8);                       \
    gl2lds16(gA + 192 * HID + _kc, (AD) + 12288 + td8);                      \
    _Pragma("unroll")                                                        \
    for (int _r = 0; _r < NJ; ++_r)                                          \
        gl2lds16(gB + (size_t)(_r * 64) * HID + _kc, (BD) + _r * 4096 + td8); } while (0)

#define LDA4(dst, AD, QB, SW) do {                                           \
    dst[0] = *(const bf16x8*)((AD) + arow0 + ((QB) + 0) * 1024 + (SW));      \
    dst[1] = *(const bf16x8*)((AD) + arow0 + ((QB) + 1) * 1024 + (SW));      \
    dst[2] = *(const bf16x8*)((AD) + arow0 + ((QB) + 2) * 1024 + (SW));      \
    dst[3] = *(const bf16x8*)((AD) + arow0 + ((QB) + 3) * 1024 + (SW)); } while (0)

#define LDB(dst, BD, SW) do {                                                \
    _Pragma("unroll")                                                        \
    for (int _n = 0; _n < NJ; ++_n)                                          \
        dst[_n] = *(const bf16x8*)((BD) + brow0 + _n * 1024 + (SW)); } while (0)

#define MF(Q, a, b) do {                                                     \
    __builtin_amdgcn_s_setprio(1);                                           \
    _Pragma("unroll")                                                        \
    for (int mi = 0; mi < 4; ++mi)                                           \
        _Pragma("unroll")                                                    \
        for (int nj = 0; nj < NJ; ++nj)                                      \
            acc[(Q) * 4 + mi][nj] =                                          \
                __builtin_amdgcn_mfma_f32_16x16x32_bf16(a[mi], b[nj],        \
                                                        acc[(Q) * 4 + mi][nj], 0, 0, 0); \
    __builtin_amdgcn_s_setprio(0); } while (0)

#define TILE(AD, BD, AN, BN_, ks) do {                                       \
    LDA4(aY, AD, 4, sw0);            /* ds: 8+NJ */                          \
    w_lgkm4();                       /* aX,b0v ready; aY rides */            \
    MF(0, aX, b0v);                                                          \
    LDA4(aX, AD, 0, sw1);                                                    \
    LDB(b1v, BD, sw1);               /* ds: aY4 + 4+NJ */                    \
    w_lgkm_4nj<NJ>();                /* aY ready */                          \
    MF(1, aY, b0v);                                                          \
    LDA4(aY, AD, 4, sw1);            /* ds: 8+NJ */                          \
    w_lgkm4();                       /* aX,b1v ready */                      \
    MF(0, aX, b1v);                                                          \
    w_lgkm0();                       /* all my (AD,BD) reads done */         \
    barx();                          /* all waves done reading (AD,BD) */    \
    STAGE(ks, AD, BD);               /* vm: old 4+NJ + new 4+NJ */           \
    w_vm_ns<NJ>();                   /* stage(t+1 -> AN,BN_) complete */     \
    barx();                          /* (AN,BN_) certified for all */        \
    LDA4(aX, AN, 0, sw0);                                                    \
    LDB(b0v, BN_, sw0);              /* next-tile kk0 reads in flight */     \
    sched0();                                                                \
    MF(1, aY, b1v);                  /* rides over next-tile reads */        \
} while (0)

    STAGE(0, A0, B0);
    STAGE(1, A1, B1);
    w_vm_ns<NJ>();
    barx();
    LDA4(aX, A0, 0, sw0);
    LDB(b0v, B0, sw0);

    for (int t = 0; t < 32; t += 2) {
        TILE(A0, B0, A1, B1, (t + 2 < 32) ? t + 2 : 31);
        TILE(A1, B1, A0, B0, (t + 3 < 32) ? t + 3 : 31);
    }
    asm volatile("s_waitcnt vmcnt(0) lgkmcnt(0)" ::: "memory");

#undef TILE
#undef STAGE
#undef LDA4
#undef LDB
#undef MF

    // ---- epilogue (pack formulas verbatim; z selected per column for fused tiles)
#pragma unroll
    for (int j = 0; j < NJ; ++j) {
        int n = n0g + wc * (16 * NJ) + j * 16 + l15;    // fused col
        int zj = (MODE == 1) ? (n >> 11) : 0;
        int nn = (MODE == 1) ? (n & 2047) : n;
        float bn = (MODE == 1)
                     ? ((zj == 0) ? bias0[nn] : (zj == 1) ? bias1[nn] : bias2[nn])
                     : bias0[nn];
        unsigned short* Cz = (zj == 0) ? C0 : (zj == 1) ? C1 : C2;
#pragma unroll
        for (int i = 0; i < 8; ++i) {
            int mb = m0 + wr * 128 + i * 16 + quad * 4;   // base row, regs = mb..mb+3
            if (MODE == 1 && zj == 2) {
                // V-pack: 4 regs = 4 consecutive keys (e=0..3) -> one ushort4.
                int b = mb >> 11, s = mb & 2047, h = nn >> 7, d = nn & 127;
                int kt = s >> 4, qv = (s >> 2) & 3, ct = d >> 4, lv = d & 15;
                size_t addr = ((((size_t)((b << 4) + h) * 128 + kt) * 4 + (ct >> 1)) * 4 + qv) * 128
                              + lv * 8 + (ct & 1) * 4;
                ushort4 o;
                o.x = f2bf(acc[i][j][0] + bn);
                o.y = f2bf(acc[i][j][1] + bn);
                o.z = f2bf(acc[i][j][2] + bn);
                o.w = f2bf(acc[i][j][3] + bn);
                *(ushort4*)&Cz[addr] = o;
            } else {
#pragma unroll
                for (int reg = 0; reg < 4; ++reg) {
                    int m = mb + reg;
                    float v = acc[i][j][reg] + bn;
                    if (MODE == 0) {
                        Cf[(size_t)m * HID + nn] = v;
                    } else {
                        int b = m >> 11, s = m & 2047, h = nn >> 7, d = nn & 127;
                        if (zj == 1) {
                            // K-pack: key=s -> (kt, lk); d -> (kk, qk, e)
                            int kt = s >> 4, lk = s & 15, kk = d >> 5, qk = (d >> 3) & 3, e = d & 7;
                            size_t addr = ((((size_t)((b << 4) + h) * 128 + kt) * 4 + kk) * 4 + qk) * 128
                                          + lk * 8 + e;
                            Cz[addr] = f2bf(v);
                        } else {
                            Cz[(size_t)(((b << 4) + h) * S_LEN + s) * HDIM + d] = f2bf(v);
                        }
                    }
                }
            }
        }
    }
}

// ---------------------------------------------------------------- flash attention (R16)
// Strip pairs (p, 127-p); 2-wave team per pair: wave0 = full strip p (p+1 tiles)
// + strip (127-p) kt [0, 64-p); wave1 = strip (127-p) kt [64-p, 128-p) (64 tiles).
// Every wave 64-65 tiles -> no early-exit occupancy decay. Block = 2 pairs.
// Strip-B merge via [64][33] LDS (stride 33 -> conflict-free), one barrier.
__launch_bounds__(256, 4)
__global__ void attn_kernel(const unsigned short* __restrict__ Qg,
                            const unsigned short* __restrict__ Kp,
                            const unsigned short* __restrict__ Vp,
                            unsigned short* __restrict__ O) {
    __shared__ float mrg[2][64][33];

    int linear = blockIdx.y * 32 + blockIdx.x;   // 0..1023
    int xcd = linear & 7;
    int u = linear >> 3;                          // 0..127
    int bh = xcd * 4 + (u & 3);                   // 4 bh per XCD (K/V 4MB ~ L2)
    int g = u >> 2;                               // 0..31
    int b = bh >> 4, h = bh & 15;

    int tid = threadIdx.x, lane = tid & 63, w = tid >> 6;
    int l15 = lane & 15, quad = lane >> 4;

    int pr   = 2 * g + (w >> 1);                  // pair 0..63
    int half = w & 1;
    int pi   = w >> 1;                            // pair slot in block (0,1)
    int sA = pr, sB = 127 - pr;
    int nA = pr + 1, nB = 128 - pr;
    int mid = 64 - pr;                            // strip-B split point, in [1,64]

    const unsigned short* Qb = Qg + (size_t)bh * (S_LEN * HDIM);
    const unsigned short* Kb = Kp + (size_t)bh * 262144 + quad * 128 + l15 * 8;
    const unsigned short* Vb = Vp + (size_t)bh * 262144 + quad * 128 + l15 * 8;

    const float k2 = 0.08838834764831845f * 1.4426950408889634f;  // scale*log2(e)

    f32x4 o_acc[8];
    float l_part;
    bf16x8 qf[4], kA[4], kB[4], v[4];

#define LOADK(dst, t) do { size_t _o = (size_t)(t) * 2048;                         \
    dst[0] = *(const bf16x8*)&Kb[_o];                                              \
    dst[1] = *(const bf16x8*)&Kb[_o + 512];                                        \
    dst[2] = *(const bf16x8*)&Kb[_o + 1024];                                       \
    dst[3] = *(const bf16x8*)&Kb[_o + 1536]; } while (0)

#define LOADV(dst, t) do { size_t _o = (size_t)(t) * 2048;                         \
    dst[0] = *(const bf16x8*)&Vb[_o];                                              \
    dst[1] = *(const bf16x8*)&Vb[_o + 512];                                        \
    dst[2] = *(const bf16x8*)&Vb[_o + 1024];                                       \
    dst[3] = *(const bf16x8*)&Vb[_o + 1536]; } while (0)

#define VLO(x) __builtin_shufflevector(x, x, 0, 1, 2, 3)
#define VHI(x) __builtin_shufflevector(x, x, 4, 5, 6, 7)

    // One K-tile: S^T = K*Q^T (A=K m=key, B=Q n=qrow); p=exp2; O += P*V.
    // lane reg r holds S[qrow][key=t*16+quad*4+r]; P is the 16x16x16 A-fragment.
#define ATILE(kreg, t, mkt) do {                                                   \
    f32x4 st0 = (f32x4){0.f, 0.f, 0.f, 0.f};                                       \
    f32x4 st1 = (f32x4){0.f, 0.f, 0.f, 0.f};                                       \
    __builtin_amdgcn_s_setprio(1);                                                 \
    st0 = __builtin_amdgcn_mfma_f32_16x16x32_bf16(kreg[0], qf[0], st0, 0, 0, 0);   \
    st1 = __builtin_amdgcn_mfma_f32_16x16x32_bf16(kreg[1], qf[1], st1, 0, 0, 0);   \
    st0 = __builtin_amdgcn_mfma_f32_16x16x32_bf16(kreg[2], qf[2], st0, 0, 0, 0);   \
    st1 = __builtin_amdgcn_mfma_f32_16x16x32_bf16(kreg[3], qf[3], st1, 0, 0, 0);   \
    __builtin_amdgcn_s_setprio(0);                                                 \
    f32x4 stv = st0 + st1;                                                         \
    float p0, p1, p2, p3;                                                          \
    if ((t) == (mkt)) {                                                            \
        p0 = (quad * 4 + 0 <= l15) ? exp2f(stv[0] * k2) : 0.f;                     \
        p1 = (quad * 4 + 1 <= l15) ? exp2f(stv[1] * k2) : 0.f;                     \
        p2 = (quad * 4 + 2 <= l15) ? exp2f(stv[2] * k2) : 0.f;                     \
        p3 = (quad * 4 + 3 <= l15) ? exp2f(stv[3] * k2) : 0.f;                     \
    } else {                                                                       \
        p0 = exp2f(stv[0] * k2); p1 = exp2f(stv[1] * k2);                          \
        p2 = exp2f(stv[2] * k2); p3 = exp2f(stv[3] * k2);                          \
    }                                                                              \
    l_part += (p0 + p1) + (p2 + p3);                                               \
    bf16x4 pf;                                                                     \
    pf[0] = (short)f2bf(p0); pf[1] = (short)f2bf(p1);                              \
    pf[2] = (short)f2bf(p2); pf[3] = (short)f2bf(p3);                              \
    __builtin_amdgcn_s_setprio(1);                                                 \
    o_acc[0] = pv_mfma(pf, VLO(v[0]), o_acc[0]);                                   \
    o_acc[1] = pv_mfma(pf, VHI(v[0]), o_acc[1]);                                   \
    o_acc[2] = pv_mfma(pf, VLO(v[1]), o_acc[2]);                                   \
    o_acc[3] = pv_mfma(pf, VHI(v[1]), o_acc[3]);                                   \
    o_acc[4] = pv_mfma(pf, VLO(v[2]), o_acc[4]);                                   \
    o_acc[5] = pv_mfma(pf, VHI(v[2]), o_acc[5]);                                   \
    o_acc[6] = pv_mfma(pf, VLO(v[3]), o_acc[6]);                                   \
    o_acc[7] = pv_mfma(pf, VHI(v[3]), o_acc[7]);                                   \
    __builtin_amdgcn_s_setprio(0);                                                 \
} while (0)

    // run tiles [lo, hi) for the strip at row r0; diagonal mask at tile mkt.
    auto run = [&](int r0, int lo, int hi, int mkt) {
#pragma unroll
        for (int kk = 0; kk < 4; ++kk)
            qf[kk] = *(const bf16x8*)&Qb[(size_t)(r0 + l15) * HDIM + kk * 32 + quad * 8];
        LOADK(kA, lo);
        int kt = lo;
        while (true) {
            int ktn = (kt + 1 < hi) ? kt + 1 : kt;
            LOADV(v, kt);
            LOADK(kB, ktn);
            ATILE(kA, kt, mkt);
            if (++kt >= hi) break;

            ktn = (kt + 1 < hi) ? kt + 1 : kt;
            LOADV(v, kt);
            LOADK(kA, ktn);
            ATILE(kB, kt, mkt);
            if (++kt >= hi) break;
        }
    };

    auto epi = [&](int r0) {
        float lp = l_part;
        lp += __shfl_xor(lp, 16, 64);
        lp += __shfl_xor(lp, 32, 64);
#pragma unroll
        for (int reg = 0; reg < 4; ++reg) {
            float l = __shfl(lp, quad * 4 + reg, 64);
            float inv = 1.f / l;
            int srow = r0 + quad * 4 + reg;
            unsigned short* op = O + (size_t)(b * S_LEN + srow) * HID + h * HDIM;
#pragma unroll
            for (int ct = 0; ct < 8; ++ct)
                op[ct * 16 + l15] = f2bf(o_acc[ct][reg] * inv);
        }
    };

    // ---- strip A: wave0 of each pair owns it entirely (p+1 tiles, diagonal last)
    if (half == 0) {
#pragma unroll
        for (int c = 0; c < 8; ++c) o_acc[c] = (f32x4){0.f, 0.f, 0.f, 0.f};
        l_part = 0.f;
        run(sA * 16, 0, nA, nA - 1);
        epi(sA * 16);
    }

    // ---- strip B: split at mid; wave1 owns the diagonal-containing suffix.
#pragma unroll
    for (int c = 0; c < 8; ++c) o_acc[c] = (f32x4){0.f, 0.f, 0.f, 0.f};
    l_part = 0.f;
    if (half == 0) run(sB * 16, 0, mid, nB - 1);
    else           run(sB * 16, mid, nB, nB - 1);

    if (half == 1) {
#pragma unroll
        for (int c = 0; c < 8; ++c) {
            mrg[pi][lane][c * 4 + 0] = o_acc[c][0];
            mrg[pi][lane][c * 4 + 1] = o_acc[c][1];
            mrg[pi][lane][c * 4 + 2] = o_acc[c][2];
            mrg[pi][lane][c * 4 + 3] = o_acc[c][3];
        }
        mrg[pi][lane][32] = l_part;
    }
    __syncthreads();
    if (half == 0) {
#pragma unroll
        for (int c = 0; c < 8; ++c) {
            o_acc[c][0] += mrg[pi][lane][c * 4 + 0];
            o_acc[c][1] += mrg[pi][lane][c * 4 + 1];
            o_acc[c][2] += mrg[pi][lane][c * 4 + 2];
            o_acc[c][3] += mrg[pi][lane][c * 4 + 3];
        }
        l_part += mrg[pi][lane][32];
        epi(sB * 16);
    }

#undef ATILE
#undef LOADK
#undef LOADV
#undef VLO
#undef VHI
}

// ---------------------------------------------------------------- launch
extern "C" void kernel_launch(void* const* d_in, const int* in_sizes, int n_in,
                              void* d_out, int out_size, void* d_ws, size_t ws_size,
                              hipStream_t stream) {
    (void)in_sizes; (void)n_in; (void)out_size; (void)ws_size;
    const float* x  = (const float*)d_in[0];
    const float* wq = (const float*)d_in[2];
    const float* bq = (const float*)d_in[3];
    const float* wk = (const float*)d_in[4];
    const float* bk = (const float*)d_in[5];
    const float* wv = (const float*)d_in[6];
    const float* bv = (const float*)d_in[7];
    const float* wo = (const float*)d_in[8];
    const float* bo = (const float*)d_in[9];
    float* out = (float*)d_out;

    unsigned short* ws = (unsigned short*)d_ws;
    const size_t WSZ = 4194304;
    unsigned short* wqT = ws;                // [0, 4M)   wqT/wkT/wvT contiguous =
    unsigned short* wkT = ws + WSZ;          // [4M, 8M)  fused [6144][2048] B for QKV
    unsigned short* wvT = ws + 2 * WSZ;      // [8M, 12M)
    unsigned short* woT = ws + 3 * WSZ;      // [12M, 16M)
    unsigned short* xb  = ws + 4 * WSZ;      // [16M, 24M)
    unsigned short* Ab  = ws + 4 * WSZ;      // aliases xb (dead after QKV gemm)
    unsigned short* Qb  = ws + 6 * WSZ;      // [24M, 32M)
    unsigned short* Kb  = ws + 8 * WSZ;      // [32M, 40M)  fragment-packed
    unsigned short* Vb  = ws + 10 * WSZ;     // [40M, 48M)  fragment-packed

    convert_x<<<dim3(8192), 256, 0, stream>>>(x, xb);
    convert_wt<<<dim3(32, 32, 4), 256, 0, stream>>>(wq, wk, wv, wo, wqT, wkT, wvT, woT);
    gemmT<1, 3><<<dim3(512), 512, 0, stream>>>(xb, wqT, bq, bk, bv,
                                               Qb, Kb, Vb, nullptr);
    attn_kernel<<<dim3(32, 32), 256, 0, stream>>>(Qb, Kb, Vb, Ab);
    gemmT<0, 2><<<dim3(256), 512, 0, stream>>>(Ab, woT, bo, nullptr, nullptr,
                                               nullptr, nullptr, nullptr, out);
}

// Round 9
// 394.704 us; speedup vs baseline: 1.0318x; 1.0199x over previous
//
#include <hip/hip_runtime.h>

// CausalSelfAttention: B=2, S=2048, H=2048, NH=16, HD=128. f32 in/out, bf16 MFMA inside.
// R17 = R14-frozen GEMM + attn K/V LDS-sharing rewrite.
// Evidence: R16 (wave balance, occupancy 2x) was NEUTRAL -> attn is K/V-BW-bound:
// 2.1GB L2 reads/call (each wave privately re-reads K/V), ~21 TB/s = 60% L2 ceiling.
// R17: block = 4 waves = 64-row Q-block (4 adjacent strips); K/V tile (8KB,
// contiguous in frag-packed layout) staged ONCE per block via global_load_lds
// (256thr x 2x16B, coalesced, wave-uniform dest + lane*16), consumed by all 4
// waves with byte-identical fragment offsets (linear 1KB wave reads, 0 conflicts).
// Balance: Q-block pair (q, 31-q) per block -> every block exactly 132 tiles.
// Grid 512 = 2 blocks/CU (mutual barrier hiding). LDS dbuf + counted vmcnt(2)
// (1-tile lookahead ~315cy > 200cy L2 latency); drain between Q-blocks.
// Causal mask generalized: doff = kt - strip (<=3 all-masked overshoot tiles).
// Traffic 2.1GB -> 540MB. Math verbatim from verified R9/R16 ATILE.
// gemmT / convert_x / convert_wt unchanged from R14 (best measured).

using bf16x8 = __attribute__((ext_vector_type(8))) short;
using bf16x4 = __attribute__((ext_vector_type(4))) short;
using f32x4  = __attribute__((ext_vector_type(4))) float;

#define S_LEN 2048
#define NHEAD 16
#define HDIM  128
#define HID   2048

__device__ __forceinline__ unsigned short f2bf(float f) {
    unsigned int u = __float_as_uint(f);
    u += 0x7fffu + ((u >> 16) & 1u);   // round-to-nearest-even
    return (unsigned short)(u >> 16);
}
__device__ __forceinline__ void gl2lds16(const void* g, void* l) {
    __builtin_amdgcn_global_load_lds(
        (const __attribute__((address_space(1))) void*)g,
        (__attribute__((address_space(3))) void*)l, 16, 0, 0);
}

// 16x16x16 bf16 MFMA, device-guarded (host pass must not reference the builtin).
__device__ __forceinline__ f32x4 pv_mfma(bf16x4 a, bf16x4 b, f32x4 c) {
#if defined(__HIP_DEVICE_COMPILE__)
#if __has_builtin(__builtin_amdgcn_mfma_f32_16x16x16bf16_1k)
    return __builtin_amdgcn_mfma_f32_16x16x16bf16_1k(a, b, c, 0, 0, 0);
#else
    asm("v_mfma_f32_16x16x16_bf16 %0, %1, %2, %0" : "+v"(c) : "v"(a), "v"(b));
    return c;
#endif
#else
    (void)a; (void)b;
    return c;
#endif
}

// ---------------------------------------------------------------- convert x: f32 -> bf16
__global__ void convert_x(const float* __restrict__ x, unsigned short* __restrict__ xb) {
    int i = (blockIdx.x * 256 + threadIdx.x) * 4;
    float4 v = *(const float4*)(x + i);
    ushort4 o;
    o.x = f2bf(v.x); o.y = f2bf(v.y); o.z = f2bf(v.z); o.w = f2bf(v.w);
    *(ushort4*)(xb + i) = o;
}

// ------------------------------------------------- convert+transpose weights: f32 -> bf16^T
__global__ void convert_wt(const float* __restrict__ w0, const float* __restrict__ w1,
                           const float* __restrict__ w2, const float* __restrict__ w3,
                           unsigned short* __restrict__ t0, unsigned short* __restrict__ t1,
                           unsigned short* __restrict__ t2, unsigned short* __restrict__ t3) {
    __shared__ float tile[64][65];
    int z = blockIdx.z;
    const float* src = (z == 0) ? w0 : (z == 1) ? w1 : (z == 2) ? w2 : w3;
    unsigned short* dst = (z == 0) ? t0 : (z == 1) ? t1 : (z == 2) ? t2 : t3;
    int r0 = blockIdx.y * 64, c0 = blockIdx.x * 64;
    int t = threadIdx.x;
    for (int i = t; i < 64 * 64; i += 256) {
        int r = i >> 6, c = i & 63;
        tile[r][c] = src[(size_t)(r0 + r) * HID + c0 + c];
    }
    __syncthreads();
    for (int i = t; i < 64 * 64; i += 256) {
        int r = i & 63, c = i >> 6;
        dst[(size_t)(c0 + c) * HID + r0 + r] = f2bf(tile[r][c]);
    }
}

// ---- counted waits (asm literals need compile-time dispatch) -----------------
__device__ __forceinline__ void sched0() { __builtin_amdgcn_sched_barrier(0); }
__device__ __forceinline__ void w_lgkm4() { asm volatile("s_waitcnt lgkmcnt(4)" ::: "memory"); sched0(); }
__device__ __forceinline__ void w_lgkm0() { asm volatile("s_waitcnt lgkmcnt(0)" ::: "memory"); sched0(); }
template <int NJ> __device__ __forceinline__ void w_lgkm_4nj() {
    if constexpr (NJ == 3) { asm volatile("s_waitcnt lgkmcnt(7)" ::: "memory"); }
    else                   { asm volatile("s_waitcnt lgkmcnt(6)" ::: "memory"); }
    sched0();
}
template <int NJ> __device__ __forceinline__ void w_vm_ns() {
    if constexpr (NJ == 3) { asm volatile("s_waitcnt vmcnt(7)" ::: "memory"); }
    else                   { asm volatile("s_waitcnt vmcnt(6)" ::: "memory"); }
    sched0();
}
__device__ __forceinline__ void w_vm2() { asm volatile("s_waitcnt vmcnt(2)" ::: "memory"); sched0(); }
__device__ __forceinline__ void w_vm0() { asm volatile("s_waitcnt vmcnt(0)" ::: "memory"); sched0(); }
__device__ __forceinline__ void barx() {
    asm volatile("" ::: "memory");
    __builtin_amdgcn_s_barrier();
    asm volatile("" ::: "memory");
}

// ---------------------------------------------------------------- GEMM 256xBN (R14, frozen)
// C[4096][N] = A @ Bt^T + bias; A,Bt bf16, fp32 acc. BN = NJ*64.
// MODE 1: fused QKV, N=6144, Bt0 = contiguous [6144][2048]. NJ=3 -> grid 512 (2 rounds).
// MODE 0: out-proj, N=2048, f32 out. NJ=2 -> grid 256 (1 round).
template <int MODE, int NJ>
__launch_bounds__(512, 2)
__global__ void gemmT(const unsigned short* __restrict__ A,
                      const unsigned short* __restrict__ Bt0,
                      const float* __restrict__ bias0,
                      const float* __restrict__ bias1,
                      const float* __restrict__ bias2,
                      unsigned short* __restrict__ C0,
                      unsigned short* __restrict__ C1,
                      unsigned short* __restrict__ C2,
                      float* __restrict__ Cf) {
    constexpr int BN = NJ * 64;
    __shared__ __align__(16) unsigned short lds[2 * 16384 + 2 * NJ * 4096];
    unsigned short* const A0 = lds;
    unsigned short* const A1 = lds + 16384;
    unsigned short* const B0 = lds + 32768;
    unsigned short* const B1 = lds + 32768 + NJ * 4096;

    const int CPX = (MODE == 1) ? 64 : 32;      // blocks per XCD (bijective: nwg%8==0)
    int vb = (blockIdx.x & 7) * CPX + (blockIdx.x >> 3);
    int m0  = (vb & 15) * 256;
    int n0g = (vb >> 4) * BN;                   // fused col (0..6143 / 0..2047)

    int tid = threadIdx.x;
    int lane = tid & 63;
    int wv_ = tid >> 6;
    int wr = wv_ >> 2, wc = wv_ & 3;            // 2x4 wave grid; wave tile 128 x (NJ*16)
    int l15 = lane & 15, quad = lane >> 4;

    int tr = tid >> 3;
    int tc = ((tid & 7) ^ (tr & 7)) << 3;
    const unsigned short* gA = A   + (size_t)(m0  + tr) * HID + tc;
    const unsigned short* gB = Bt0 + (size_t)(n0g + tr) * HID + tc;
    const int td8 = tid * 8;

    int arow0 = (wr * 128 + l15) * 64;          // + mi*1024
    int brow0 = (wc * (16 * NJ) + l15) * 64;    // + nj*1024
    int sw0 = ((quad ^ (l15 & 7)) << 3);        // kk=0
    int sw1 = (((4 + quad) ^ (l15 & 7)) << 3);  // kk=1

    f32x4 acc[8][NJ];
#pragma unroll
    for (int i = 0; i < 8; ++i)
#pragma unroll
        for (int j = 0; j < NJ; ++j) acc[i][j] = (f32x4){0.f, 0.f, 0.f, 0.f};

    bf16x8 aX[4], aY[4], b0v[NJ], b1v[NJ];

#define STAGE(kt, AD, BD) do { int _kc = (kt) * 64;                          \
    gl2lds16(gA + _kc,             (AD) + td8);                              \
    gl2lds16(gA + 64 * HID + _kc,  (AD) + 4096 + td8);                       \
    gl2lds16(gA + 128 * HID + _kc, (AD) + 8192 + td8);                       \
    gl2lds16(gA + 192 * HID + _kc, (AD) + 12288 + td8);                      \
    _Pragma("unroll")                                                        \
    for (int _r = 0; _r < NJ; ++_r)                                          \
        gl2lds16(gB + (size_t)(_r * 64) * HID + _kc, (BD) + _r * 4096 + td8); } while (0)

#define LDA4(dst, AD, QB, SW) do {                                           \
    dst[0] = *(const bf16x8*)((AD) + arow0 + ((QB) + 0) * 1024 + (SW));      \
    dst[1] = *(const bf16x8*)((AD) + arow0 + ((QB) + 1) * 1024 + (SW));      \
    dst[2] = *(const bf16x8*)((AD) + arow0 + ((QB) + 2) * 1024 + (SW));      \
    dst[3] = *(const bf16x8*)((AD) + arow0 + ((QB) + 3) * 1024 + (SW)); } while (0)

#define LDB(dst, BD, SW) do {                                                \
    _Pragma("unroll")                                                        \
    for (int _n = 0; _n < NJ; ++_n)                                          \
        dst[_n] = *(const bf16x8*)((BD) + brow0 + _n * 1024 + (SW)); } while (0)

#define MF(Q, a, b) do {                                                     \
    __builtin_amdgcn_s_setprio(1);                                           \
    _Pragma("unroll")                                                        \
    for (int mi = 0; mi < 4; ++mi)                                           \
        _Pragma("unroll")                                                    \
        for (int nj = 0; nj < NJ; ++nj)                                      \
            acc[(Q) * 4 + mi][nj] =                                          \
                __builtin_amdgcn_mfma_f32_16x16x32_bf16(a[mi], b[nj],        \
                                                        acc[(Q) * 4 + mi][nj], 0, 0, 0); \
    __builtin_amdgcn_s_setprio(0); } while (0)

#define TILE(AD, BD, AN, BN_, ks) do {                                       \
    LDA4(aY, AD, 4, sw0);            /* ds: 8+NJ */                          \
    w_lgkm4();                       /* aX,b0v ready; aY rides */            \
    MF(0, aX, b0v);                                                          \
    LDA4(aX, AD, 0, sw1);                                                    \
    LDB(b1v, BD, sw1);               /* ds: aY4 + 4+NJ */                    \
    w_lgkm_4nj<NJ>();                /* aY ready */                          \
    MF(1, aY, b0v);                                                          \
    LDA4(aY, AD, 4, sw1);            /* ds: 8+NJ */                          \
    w_lgkm4();                       /* aX,b1v ready */                      \
    MF(0, aX, b1v);                                                          \
    w_lgkm0();                       /* all my (AD,BD) reads done */         \
    barx();                          /* all waves done reading (AD,BD) */    \
    STAGE(ks, AD, BD);               /* vm: old 4+NJ + new 4+NJ */           \
    w_vm_ns<NJ>();                   /* stage(t+1 -> AN,BN_) complete */     \
    barx();                          /* (AN,BN_) certified for all */        \
    LDA4(aX, AN, 0, sw0);                                                    \
    LDB(b0v, BN_, sw0);              /* next-tile kk0 reads in flight */     \
    sched0();                                                                \
    MF(1, aY, b1v);                  /* rides over next-tile reads */        \
} while (0)

    STAGE(0, A0, B0);
    STAGE(1, A1, B1);
    w_vm_ns<NJ>();
    barx();
    LDA4(aX, A0, 0, sw0);
    LDB(b0v, B0, sw0);

    for (int t = 0; t < 32; t += 2) {
        TILE(A0, B0, A1, B1, (t + 2 < 32) ? t + 2 : 31);
        TILE(A1, B1, A0, B0, (t + 3 < 32) ? t + 3 : 31);
    }
    asm volatile("s_waitcnt vmcnt(0) lgkmcnt(0)" ::: "memory");

#undef TILE
#undef STAGE
#undef LDA4
#undef LDB
#undef MF

    // ---- epilogue (pack formulas verbatim; z selected per column for fused tiles)
#pragma unroll
    for (int j = 0; j < NJ; ++j) {
        int n = n0g + wc * (16 * NJ) + j * 16 + l15;    // fused col
        int zj = (MODE == 1) ? (n >> 11) : 0;
        int nn = (MODE == 1) ? (n & 2047) : n;
        float bn = (MODE == 1)
                     ? ((zj == 0) ? bias0[nn] : (zj == 1) ? bias1[nn] : bias2[nn])
                     : bias0[nn];
        unsigned short* Cz = (zj == 0) ? C0 : (zj == 1) ? C1 : C2;
#pragma unroll
        for (int i = 0; i < 8; ++i) {
            int mb = m0 + wr * 128 + i * 16 + quad * 4;   // base row, regs = mb..mb+3
            if (MODE == 1 && zj == 2) {
                // V-pack: 4 regs = 4 consecutive keys (e=0..3) -> one ushort4.
                int b = mb >> 11, s = mb & 2047, h = nn >> 7, d = nn & 127;
                int kt = s >> 4, qv = (s >> 2) & 3, ct = d >> 4, lv = d & 15;
                size_t addr = ((((size_t)((b << 4) + h) * 128 + kt) * 4 + (ct >> 1)) * 4 + qv) * 128
                              + lv * 8 + (ct & 1) * 4;
                ushort4 o;
                o.x = f2bf(acc[i][j][0] + bn);
                o.y = f2bf(acc[i][j][1] + bn);
                o.z = f2bf(acc[i][j][2] + bn);
                o.w = f2bf(acc[i][j][3] + bn);
                *(ushort4*)&Cz[addr] = o;
            } else {
#pragma unroll
                for (int reg = 0; reg < 4; ++reg) {
                    int m = mb + reg;
                    float v = acc[i][j][reg] + bn;
                    if (MODE == 0) {
                        Cf[(size_t)m * HID + nn] = v;
                    } else {
                        int b = m >> 11, s = m & 2047, h = nn >> 7, d = nn & 127;
                        if (zj == 1) {
                            // K-pack: key=s -> (kt, lk); d -> (kk, qk, e)
                            int kt = s >> 4, lk = s & 15, kk = d >> 5, qk = (d >> 3) & 3, e = d & 7;
                            size_t addr = ((((size_t)((b << 4) + h) * 128 + kt) * 4 + kk) * 4 + qk) * 128
                                          + lk * 8 + e;
                            Cz[addr] = f2bf(v);
                        } else {
                            Cz[(size_t)(((b << 4) + h) * S_LEN + s) * HDIM + d] = f2bf(v);
                        }
                    }
                }
            }
        }
    }
}

// ---------------------------------------------------------------- flash attention (R17)
// Block = 4 waves = 64-row Q-block (4 adjacent strips). K/V tile (8KB) staged once
// per block into LDS (dbuf, counted vmcnt(2), 1-tile lookahead). Q-block pair
// (q, 31-q) per block -> exactly 132 tiles every block. Grid 512 = 2 blocks/CU.
__launch_bounds__(256, 2)
__global__ void attn_kernel(const unsigned short* __restrict__ Qg,
                            const unsigned short* __restrict__ Kp,
                            const unsigned short* __restrict__ Vp,
                            unsigned short* __restrict__ O) {
    __shared__ __align__(16) unsigned short kv[2][4096];   // [buf][K:0..2048 | V:2048..4096]

    int linear = blockIdx.x;                  // 0..511
    int xcd = linear & 7;
    int u = linear >> 3;                      // 0..63
    int bh = xcd * 4 + (u & 3);               // 4 bh per XCD (K/V 4MB ~ L2)
    int q = u >> 2;                           // 0..15 -> pair (q, 31-q)
    int b = bh >> 4, h = bh & 15;

    int tid = threadIdx.x, lane = tid & 63, w = tid >> 6;
    int l15 = lane & 15, quad = lane >> 4;

    const unsigned short* Qb = Qg + (size_t)bh * (S_LEN * HDIM);
    const unsigned short* Kg = Kp + (size_t)bh * 262144;
    const unsigned short* Vg = Vp + (size_t)bh * 262144;
    const float k2 = 0.08838834764831845f * 1.4426950408889634f;  // scale*log2(e)

    const int frag = quad * 128 + l15 * 8;    // in-tile fragment offset (elems)
    const int td8 = tid * 8;                  // staging offset: tid*16B

#define VLO(x) __builtin_shufflevector(x, x, 0, 1, 2, 3)
#define VHI(x) __builtin_shufflevector(x, x, 4, 5, 6, 7)
#define ASTAGE(kt, bf) do { size_t _g = (size_t)(kt) * 2048 + td8;             \
    gl2lds16(Kg + _g, &kv[bf][td8]);                                           \
    gl2lds16(Vg + _g, &kv[bf][2048 + td8]); } while (0)

    auto run_qblock = [&](int qb) {
        int s  = 4 * qb + w;                  // my strip (diagonal tile = s)
        int r0 = s * 16;
        int N  = 4 * qb + 4;                  // staged tiles (block-uniform)

        bf16x8 qf[4];
#pragma unroll
        for (int kk = 0; kk < 4; ++kk)
            qf[kk] = *(const bf16x8*)&Qb[(size_t)(r0 + l15) * HDIM + kk * 32 + quad * 8];

        f32x4 o_acc[8];
#pragma unroll
        for (int c = 0; c < 8; ++c) o_acc[c] = (f32x4){0.f, 0.f, 0.f, 0.f};
        float l_part = 0.f;

        ASTAGE(0, 0);
        for (int kt = 0; kt < N; ++kt) {
            int nk = (kt + 1 < N) ? kt + 1 : kt;      // uniform dummy re-stage at end
            ASTAGE(nk, (kt + 1) & 1);
            w_vm2();                                  // my 2 ops of stage(kt) done
            barx();                                   // all waves: tile kt staged

            const unsigned short* KL = &kv[kt & 1][frag];
            const unsigned short* VL = &kv[kt & 1][2048 + frag];
            bf16x8 kb0 = *(const bf16x8*)(KL);
            bf16x8 kb1 = *(const bf16x8*)(KL + 512);
            bf16x8 kb2 = *(const bf16x8*)(KL + 1024);
            bf16x8 kb3 = *(const bf16x8*)(KL + 1536);
            bf16x8 v0 = *(const bf16x8*)(VL);
            bf16x8 v1 = *(const bf16x8*)(VL + 512);
            bf16x8 v2 = *(const bf16x8*)(VL + 1024);
            bf16x8 v3 = *(const bf16x8*)(VL + 1536);

            f32x4 st0 = (f32x4){0.f, 0.f, 0.f, 0.f};
            f32x4 st1 = (f32x4){0.f, 0.f, 0.f, 0.f};
            __builtin_amdgcn_s_setprio(1);
            st0 = __builtin_amdgcn_mfma_f32_16x16x32_bf16(kb0, qf[0], st0, 0, 0, 0);
            st1 = __builtin_amdgcn_mfma_f32_16x16x32_bf16(kb1, qf[1], st1, 0, 0, 0);
            st0 = __builtin_amdgcn_mfma_f32_16x16x32_bf16(kb2, qf[2], st0, 0, 0, 0);
            st1 = __builtin_amdgcn_mfma_f32_16x16x32_bf16(kb3, qf[3], st1, 0, 0, 0);
            __builtin_amdgcn_s_setprio(0);
            f32x4 stv = st0 + st1;

            // lane reg r holds S[qrow=r0+l15][key=16*kt+quad*4+r]
            float p0, p1, p2, p3;
            int doff = kt - s;                        // wave-uniform
            if (doff >= 0) {                          // diagonal (=0) or overshoot (>0: all 0)
                int d16 = doff << 4;
                p0 = (d16 + quad * 4 + 0 <= l15) ? exp2f(stv[0] * k2) : 0.f;
                p1 = (d16 + quad * 4 + 1 <= l15) ? exp2f(stv[1] * k2) : 0.f;
                p2 = (d16 + quad * 4 + 2 <= l15) ? exp2f(stv[2] * k2) : 0.f;
                p3 = (d16 + quad * 4 + 3 <= l15) ? exp2f(stv[3] * k2) : 0.f;
            } else {
                p0 = exp2f(stv[0] * k2); p1 = exp2f(stv[1] * k2);
                p2 = exp2f(stv[2] * k2); p3 = exp2f(stv[3] * k2);
            }
            l_part += (p0 + p1) + (p2 + p3);

            bf16x4 pf;
            pf[0] = (short)f2bf(p0); pf[1] = (short)f2bf(p1);
            pf[2] = (short)f2bf(p2); pf[3] = (short)f2bf(p3);

            __builtin_amdgcn_s_setprio(1);
            o_acc[0] = pv_mfma(pf, VLO(v0), o_acc[0]);
            o_acc[1] = pv_mfma(pf, VHI(v0), o_acc[1]);
            o_acc[2] = pv_mfma(pf, VLO(v1), o_acc[2]);
            o_acc[3] = pv_mfma(pf, VHI(v1), o_acc[3]);
            o_acc[4] = pv_mfma(pf, VLO(v2), o_acc[4]);
            o_acc[5] = pv_mfma(pf, VHI(v2), o_acc[5]);
            o_acc[6] = pv_mfma(pf, VLO(v3), o_acc[6]);
            o_acc[7] = pv_mfma(pf, VHI(v3), o_acc[7]);
            __builtin_amdgcn_s_setprio(0);
            barx();                                   // reads of buf[kt&1] done
        }
        w_vm0();                                      // drain dummy stage
        barx();                                       // buffers clean for next qblock

        // ---- epilogue: normalizer over quads, write O rows r0..r0+15
        float lp = l_part;
        lp += __shfl_xor(lp, 16, 64);
        lp += __shfl_xor(lp, 32, 64);
#pragma unroll
        for (int reg = 0; reg < 4; ++reg) {
            float l = __shfl(lp, quad * 4 + reg, 64);
            float inv = 1.f / l;
            int srow = r0 + quad * 4 + reg;
            unsigned short* op = O + (size_t)(b * S_LEN + srow) * HID + h * HDIM;
#pragma unroll
            for (int ct = 0; ct < 8; ++ct)
                op[ct * 16 + l15] = f2bf(o_acc[ct][reg] * inv);
        }
    };

    run_qblock(q);        // 4q+4 tiles
    run_qblock(31 - q);   // 128-4q tiles  (total 132, every block)

#undef ASTAGE
#undef VLO
#undef VHI
}

// ---------------------------------------------------------------- launch
extern "C" void kernel_launch(void* const* d_in, const int* in_sizes, int n_in,
                              void* d_out, int out_size, void* d_ws, size_t ws_size,
                              hipStream_t stream) {
    (void)in_sizes; (void)n_in; (void)out_size; (void)ws_size;
    const float* x  = (const float*)d_in[0];
    const float* wq = (const float*)d_in[2];
    const float* bq = (const float*)d_in[3];
    const float* wk = (const float*)d_in[4];
    const float* bk = (const float*)d_in[5];
    const float* wv = (const float*)d_in[6];
    const float* bv = (const float*)d_in[7];
    const float* wo = (const float*)d_in[8];
    const float* bo = (const float*)d_in[9];
    float* out = (float*)d_out;

    unsigned short* ws = (unsigned short*)d_ws;
    const size_t WSZ = 4194304;
    unsigned short* wqT = ws;                // [0, 4M)   wqT/wkT/wvT contiguous =
    unsigned short* wkT = ws + WSZ;          // [4M, 8M)  fused [6144][2048] B for QKV
    unsigned short* wvT = ws + 2 * WSZ;      // [8M, 12M)
    unsigned short* woT = ws + 3 * WSZ;      // [12M, 16M)
    unsigned short* xb  = ws + 4 * WSZ;      // [16M, 24M)
    unsigned short* Ab  = ws + 4 * WSZ;      // aliases xb (dead after QKV gemm)
    unsigned short* Qb  = ws + 6 * WSZ;      // [24M, 32M)
    unsigned short* Kb  = ws + 8 * WSZ;      // [32M, 40M)  fragment-packed
    unsigned short* Vb  = ws + 10 * WSZ;     // [40M, 48M)  fragment-packed

    convert_x<<<dim3(8192), 256, 0, stream>>>(x, xb);
    convert_wt<<<dim3(32, 32, 4), 256, 0, stream>>>(wq, wk, wv, wo, wqT, wkT, wvT, woT);
    gemmT<1, 3><<<dim3(512), 512, 0, stream>>>(xb, wqT, bq, bk, bv,
                                               Qb, Kb, Vb, nullptr);
    attn_kernel<<<dim3(512), 256, 0, stream>>>(Qb, Kb, Vb, Ab);
    gemmT<0, 2><<<dim3(256), 512, 0, stream>>>(Ab, woT, bo, nullptr, nullptr,
                                               nullptr, nullptr, nullptr, out);
}